// Round 5
// baseline (495.842 us; speedup 1.0000x reference)
//
#include <hip/hip_runtime.h>
#include <hip/hip_bf16.h>
#include <stdint.h>

// Problem constants: B=4, T=2048, C=1024, E=8, H=2048, K=2
#define NB 4
#define NTT 2048
#define NC 1024
#define NE 8
#define NH 2048
#define NKK 2
#define NTOK (NB * NTT)            // 8192
#define CAP (2 * NTOK * NKK / NE)  // 4096

typedef __hip_bfloat16 bf16;
typedef __attribute__((ext_vector_type(8))) short short8;
typedef __attribute__((ext_vector_type(4))) short short4v;
typedef __attribute__((ext_vector_type(4))) float floatx4;
typedef __attribute__((ext_vector_type(2))) float floatx2;

typedef const __attribute__((address_space(1))) void* gas_ptr;
typedef __attribute__((address_space(3))) void* las_ptr;

static __device__ __forceinline__ void async_copy16(const void* g, void* l) {
  // 16B/lane; LDS dest = wave-uniform base + lane*16 (m97/m104 semantics).
  __builtin_amdgcn_global_load_lds((gas_ptr)g, (las_ptr)l, 16, 0, 0);
}

static __device__ __forceinline__ unsigned short f2b(float f) {
  bf16 h = __float2bfloat16(f);
  unsigned short u;
  __builtin_memcpy(&u, &h, 2);
  return u;
}
static __device__ __forceinline__ int iclamp(int v, int lo, int hi) {
  return v < lo ? lo : (v > hi ? hi : v);
}

__global__ __launch_bounds__(256) void zero_out_kernel(float* __restrict__ out) {
  const size_t i = ((size_t)blockIdx.x * 256 + threadIdx.x) * 4;
  floatx4 z = {0.f, 0.f, 0.f, 0.f};
  *reinterpret_cast<floatx4*>(out + i) = z;
}

// f32 -> bf16 (RNE), 8 elements/thread. n must be divisible by grid*256*8.
__global__ __launch_bounds__(256) void cvt_kernel(const float* __restrict__ src,
                                                  bf16* __restrict__ dst) {
  const size_t i = ((size_t)blockIdx.x * 256 + threadIdx.x) * 8;
  const floatx4 a = *reinterpret_cast<const floatx4*>(src + i);
  const floatx4 b = *reinterpret_cast<const floatx4*>(src + i + 4);
  short8 r;
  r[0] = (short)f2b(a[0]); r[1] = (short)f2b(a[1]);
  r[2] = (short)f2b(a[2]); r[3] = (short)f2b(a[3]);
  r[4] = (short)f2b(b[0]); r[5] = (short)f2b(b[1]);
  r[6] = (short)f2b(b[2]); r[7] = (short)f2b(b[3]);
  *reinterpret_cast<short8*>(dst + i) = r;
}

// Router v3 (atomic-free; round-2 fix for the 196-us cnt[] cacheline chain).
// Writes packed top-2 (epair) + normalized weights (wpair); slot assignment
// moved to build_kernel (scan). Emits x_bf16 (free: x is read anyway).
__global__ __launch_bounds__(256) void router_kernel(
    const float* __restrict__ x, const float* __restrict__ rw,
    float* __restrict__ rw_out, int* __restrict__ epair,
    float* __restrict__ wpair, bf16* __restrict__ xb) {
  __shared__ float rws[NE * NC];  // 32 KB
  const int tid = threadIdx.x;
  {
    const floatx4* rw4 = reinterpret_cast<const floatx4*>(rw);
    floatx4* rwl4 = reinterpret_cast<floatx4*>(rws);
#pragma unroll
    for (int i = 0; i < 8; ++i) rwl4[i * 256 + tid] = rw4[i * 256 + tid];
  }
  __syncthreads();

  const int wave = tid >> 6;
  const int lane = tid & 63;
  const int t = blockIdx.x * 4 + wave;
  const floatx4* xr4 = reinterpret_cast<const floatx4*>(x + (size_t)t * NC);
  const floatx4* rwl4 = reinterpret_cast<const floatx4*>(rws);
  bf16* xbr = xb + (size_t)t * NC;

  floatx4 xv[4];
#pragma unroll
  for (int i = 0; i < 4; ++i) xv[i] = xr4[i * 64 + lane];

#pragma unroll
  for (int i = 0; i < 4; ++i) {
    const int idx = i * 64 + lane;
    short4v o;
    o[0] = (short)f2b(xv[i][0]); o[1] = (short)f2b(xv[i][1]);
    o[2] = (short)f2b(xv[i][2]); o[3] = (short)f2b(xv[i][3]);
    *reinterpret_cast<short4v*>(xbr + idx * 4) = o;
  }

  float acc[NE];
#pragma unroll
  for (int e = 0; e < NE; ++e) acc[e] = 0.f;
#pragma unroll
  for (int i = 0; i < 4; ++i) {
    const int idx = i * 64 + lane;
#pragma unroll
    for (int e = 0; e < NE; ++e) {
      const floatx4 wv = rwl4[e * 256 + idx];
      acc[e] = fmaf(xv[i][0], wv[0], acc[e]);
      acc[e] = fmaf(xv[i][1], wv[1], acc[e]);
      acc[e] = fmaf(xv[i][2], wv[2], acc[e]);
      acc[e] = fmaf(xv[i][3], wv[3], acc[e]);
    }
  }
#pragma unroll
  for (int e = 0; e < NE; ++e) {
#pragma unroll
    for (int off = 32; off; off >>= 1) acc[e] += __shfl_xor(acc[e], off, 64);
  }

  float m = acc[0];
#pragma unroll
  for (int e = 1; e < NE; ++e) m = fmaxf(m, acc[e]);
  float p[NE];
  float s = 0.f;
#pragma unroll
  for (int e = 0; e < NE; ++e) {
    p[e] = __expf(acc[e] - m);
    s += p[e];
  }
  const float inv = 1.f / s;
#pragma unroll
  for (int e = 0; e < NE; ++e) p[e] *= inv;

  if (lane < NE) rw_out[(size_t)t * NE + lane] = p[lane];

  if (lane == 0) {
    int i0 = 0;
    float v0 = p[0];
    int i1 = -1;
    float v1 = -1.f;
#pragma unroll
    for (int e = 1; e < NE; ++e) {
      if (p[e] > v0) {
        v1 = v0; i1 = i0;
        v0 = p[e]; i0 = e;
      } else if (p[e] > v1) {
        v1 = p[e]; i1 = e;
      }
    }
    i0 = iclamp(i0, 0, NE - 1);
    i1 = iclamp(i1, 0, NE - 1);
    const float denom = v0 + v1 + 1e-10f;
    epair[t] = i0 | (i1 << 16);
    floatx2 wv;
    wv[0] = v0 / denom;
    wv[1] = v1 / denom;
    *reinterpret_cast<floatx2*>(wpair + 2 * t) = wv;
  }
}

// One block per expert; contiguous 32-token chunks per thread; block scan ->
// slot bases. Slot order = flat-index order = reference stable argsort,
// including capacity-overflow drop order. Zero global atomics.
__global__ __launch_bounds__(256) void build_kernel(
    const int* __restrict__ epair, const float* __restrict__ wpair,
    int* __restrict__ cnt, int* __restrict__ tok, float* __restrict__ wslot) {
  const int e = blockIdx.x;
  const int tid = threadIdx.x;
  const int lane = tid & 63;
  const int wave = tid >> 6;
  constexpr int TPT = NTOK / 256;  // 32 tokens per thread
  const int t0 = tid * TPT;

  int pe[TPT];
#pragma unroll
  for (int i = 0; i < TPT; i += 4) {
    const int4 v = *reinterpret_cast<const int4*>(epair + t0 + i);
    pe[i] = v.x; pe[i + 1] = v.y; pe[i + 2] = v.z; pe[i + 3] = v.w;
  }
  int c = 0;
#pragma unroll
  for (int i = 0; i < TPT; ++i)
    c += (((pe[i] & 0xffff) == e) ? 1 : 0) + (((pe[i] >> 16) == e) ? 1 : 0);

  int incl = c;
#pragma unroll
  for (int off = 1; off < 64; off <<= 1) {
    const int up = __shfl_up(incl, off, 64);
    if (lane >= off) incl += up;
  }
  __shared__ int wsum[4];
  if (lane == 63) wsum[wave] = incl;
  __syncthreads();
  int base = incl - c;
#pragma unroll
  for (int w = 0; w < 4; ++w)
    if (w < wave) base += wsum[w];
  if (tid == 255) cnt[e] = base + c;  // total (may exceed CAP; gemm clamps)

#pragma unroll
  for (int i = 0; i < TPT; ++i) {
    const int t = t0 + i;
    if ((pe[i] & 0xffff) == e) {
      if (base < CAP) {
        tok[e * CAP + base] = t;
        wslot[e * CAP + base] = wpair[2 * t];
      }
      ++base;
    }
    if ((pe[i] >> 16) == e) {
      if (base < CAP) {
        tok[e * CAP + base] = t;
        wslot[e * CAP + base] = wpair[2 * t + 1];
      }
      ++base;
    }
  }
}

// Grouped GEMM v3 (round-5): 256x256 tile, BK=64, 512 threads = 8 waves
// (2M x 4N), per-wave 128x64. FINE-PHASE schedule (T3+T4, m201/m248): each
// K-tile = 4 quadrant-phases {ds_read frags; [ph0: stage next tile, 8 async
// loads]; [ph3: vmcnt(0), ~3 phases after issue => satisfied]; barrier;
// lgkmcnt(0)+sched_barrier; setprio(1) 16 MFMA setprio(0); barrier}.
// Round-4's coarse 2-phase+vmcnt(8) was the documented m196 anti-pattern
// (-7..27%); this is the proven fine interleave. A-frags reg-cached across
// the 2 phases of each kk (24 ds_reads/tile, minimal). Chunk-XOR swizzle
// on the GLOBAL source side (0 bank conflicts, proven).
// Grid is FLAT 1D with e = bid & 7: all blocks of one expert land on one
// XCD (round-robin dispatch) -> A gather + B panel become XCD-L2-resident
// (round-4 FETCH=164MB vs 67MB unique was cross-XCD xb re-fetch).
// FC=1: A = x_bf16 gathered via tok, relu^2 -> hidden chunk (bf16).
// FC=0: A = hidden chunk, epilogue f32 atomicAdd of w*val into out.
template <bool FC>
__global__ __launch_bounds__(512, 2) void gemm_moe(
    const bf16* __restrict__ Axb, const bf16* __restrict__ Ah,
    const bf16* __restrict__ Bw, bf16* __restrict__ Oh,
    float* __restrict__ Oo, const int* __restrict__ cnt,
    const int* __restrict__ tok, const float* __restrict__ wslot,
    int rowOffset, int mch) {
  constexpr int Kd = FC ? NC : NH;
  constexpr int Nd = FC ? NH : NC;
  constexpr int NXB = Nd / 256;  // col blocks: 8 (fc) / 4 (proj)

  const int bid = blockIdx.x;
  const int e = bid & 7;         // expert -> XCD co-residency
  const int rest = bid >> 3;
  const int xb_ = rest % NXB;
  const int yb_ = rest / NXB;

  const int Me = iclamp(cnt[e], 0, CAP);
  const int rowBase = rowOffset + yb_ * 256;  // expert-local row
  if (rowBase >= Me) return;
  const int colBase = xb_ * 256;

  const bf16* __restrict__ Be = Bw + (size_t)e * Nd * Kd;
  const bf16* __restrict__ Ahc = Ah + (size_t)e * mch * NH;

  __shared__ bf16 As[2][256 * 64];  // 2 x 32 KB
  __shared__ bf16 Bs[2][256 * 64];  // 2 x 32 KB

  const int tid = threadIdx.x;  // 0..511
  const int lane = tid & 63;
  const int wid = tid >> 6;   // 0..7
  const int wm = wid & 1;     // M half (128 rows)
  const int wn = wid >> 1;    // N quarter (64 cols)
  const int ml = lane & 15;
  const int quad = lane >> 4;

  // Staging: slot sidx in [0,2048): row r = sidx>>3, phys chunk pc = sidx&7;
  // data placed there is logical chunk lc = pc ^ (r&7). Pointers hoisted so
  // in-loop VMEM ops are EXACTLY the 8 global_load_lds per thread per tile.
  const bf16* ga[4];
  const bf16* gb[4];
  int lofs[4];
#pragma unroll
  for (int it = 0; it < 4; ++it) {
    const int sidx = it * 512 + tid;
    const int r = sidx >> 3;  // 0..255
    const int pc = sidx & 7;
    const int lc = pc ^ (r & 7);
    if (FC) {
      const int grow = rowBase + r;
      const int tk = (grow < Me) ? tok[e * CAP + grow] : 0;
      const int arow = iclamp(tk, 0, NTOK - 1);  // global token row in x_bf16
      ga[it] = Axb + (size_t)arow * NC + lc * 8;
    } else {
      int grow = rowBase + r;
      if (grow > Me - 1) grow = Me - 1;
      const int arow = iclamp(grow - rowOffset, 0, mch - 1);  // chunk-local
      ga[it] = Ahc + (size_t)arow * NH + lc * 8;
    }
    gb[it] = Be + (size_t)(colBase + r) * Kd + lc * 8;
    lofs[it] = sidx * 8;  // element offset in As[b]/Bs[b]
  }

  floatx4 acc[8][4];
#pragma unroll
  for (int mt = 0; mt < 8; ++mt)
#pragma unroll
    for (int nt = 0; nt < 4; ++nt) acc[mt][nt] = floatx4{0.f, 0.f, 0.f, 0.f};

  // Fragment LDS element offsets for kk=0 (q=quad); kk=1 is ^32.
  int aoff[8], boff[4];
#pragma unroll
  for (int mt = 0; mt < 8; ++mt) {
    const int ra = wm * 128 + mt * 16 + ml;
    aoff[mt] = (ra * 8 + (quad ^ (ra & 7))) * 8;
  }
#pragma unroll
  for (int nt = 0; nt < 4; ++nt) {
    const int rb = wn * 64 + nt * 16 + ml;
    boff[nt] = (rb * 8 + (quad ^ (rb & 7))) * 8;
  }

  // Prologue: stage tile 0 -> buf 0, drain, barrier (all waves see it).
#pragma unroll
  for (int it = 0; it < 4; ++it) async_copy16(ga[it], &As[0][lofs[it]]);
#pragma unroll
  for (int it = 0; it < 4; ++it) async_copy16(gb[it], &Bs[0][lofs[it]]);
  asm volatile("s_waitcnt vmcnt(0)" ::: "memory");
  __builtin_amdgcn_s_barrier();

  const int nkb = Kd >> 6;
  short8 af[8];
  for (int kt = 0; kt < nkb; ++kt) {
    const int b = kt & 1;
    const bf16* __restrict__ Ab = As[b];
    const bf16* __restrict__ Bb = Bs[b];
#pragma unroll
    for (int ph = 0; ph < 4; ++ph) {
      const int kk = ph >> 1;   // K half (x32 elements)
      const int nh = ph & 1;    // N half of the wave's 4 nt
      const int xr = kk * 32;
      if (nh == 0) {
#pragma unroll
        for (int mt = 0; mt < 8; ++mt)
          af[mt] = *reinterpret_cast<const short8*>(&Ab[aoff[mt] ^ xr]);
      }
      short8 b0 = *reinterpret_cast<const short8*>(&Bb[boff[2 * nh] ^ xr]);
      short8 b1 = *reinterpret_cast<const short8*>(&Bb[boff[2 * nh + 1] ^ xr]);
      if (ph == 0 && kt + 1 < nkb) {
        // Stage tile kt+1 into buf b^1: issued after the end-barrier of
        // kt-1's last phase => all prior reads of b^1 retired. Lands before
        // the ph3 vmcnt(0) (~3 phases later => wait ~free).
        const int k0 = (kt + 1) << 6;
#pragma unroll
        for (int it = 0; it < 4; ++it)
          async_copy16(ga[it] + k0, &As[b ^ 1][lofs[it]]);
#pragma unroll
        for (int it = 0; it < 4; ++it)
          async_copy16(gb[it] + k0, &Bs[b ^ 1][lofs[it]]);
      }
      if (ph == 3) asm volatile("s_waitcnt vmcnt(0)" ::: "memory");
      __builtin_amdgcn_s_barrier();
      asm volatile("s_waitcnt lgkmcnt(0)" ::: "memory");
      __builtin_amdgcn_sched_barrier(0);  // rule #18: pin MFMA after the wait
      __builtin_amdgcn_s_setprio(1);
#pragma unroll
      for (int mt = 0; mt < 8; ++mt) {
        acc[mt][2 * nh] = __builtin_amdgcn_mfma_f32_16x16x32_bf16(
            af[mt], b0, acc[mt][2 * nh], 0, 0, 0);
        acc[mt][2 * nh + 1] = __builtin_amdgcn_mfma_f32_16x16x32_bf16(
            af[mt], b1, acc[mt][2 * nh + 1], 0, 0, 0);
      }
      __builtin_amdgcn_s_setprio(0);
      __builtin_amdgcn_s_barrier();  // phase-end: separates next staging
      __builtin_amdgcn_sched_barrier(0);
    }
  }

  // Epilogue: C/D layout col=lane&15, row=quad*4+reg (m89/m91 verified).
  if (FC) {
    bf16* __restrict__ O = Oh + (size_t)e * mch * NH;
    const int rlBase = rowBase - rowOffset;  // chunk-local
#pragma unroll
    for (int mt = 0; mt < 8; ++mt) {
      const int rl = wm * 128 + mt * 16 + quad * 4;
#pragma unroll
      for (int nt = 0; nt < 4; ++nt) {
        const int cc = colBase + wn * 64 + nt * 16 + ml;
        const floatx4 v = acc[mt][nt];
#pragma unroll
        for (int rg = 0; rg < 4; ++rg) {
          if (rowBase + rl + rg < Me) {
            float f = fmaxf(v[rg], 0.f);
            f = f * f;  // relu^2
            O[(size_t)(rlBase + rl + rg) * NH + cc] = __float2bfloat16(f);
          }
        }
      }
    }
  } else {
#pragma unroll
    for (int mt = 0; mt < 8; ++mt) {
      const int rl = wm * 128 + mt * 16 + quad * 4;
#pragma unroll
      for (int rg = 0; rg < 4; ++rg) {
        const int re = rowBase + rl + rg;  // expert-local row
        if (re < Me) {
          const int t = iclamp(tok[e * CAP + re], 0, NTOK - 1);
          const float w = wslot[e * CAP + re];
#pragma unroll
          for (int nt = 0; nt < 4; ++nt) {
            const int cc = colBase + wn * 64 + nt * 16 + ml;
            atomicAdd(Oo + (size_t)t * NC + cc, w * acc[mt][nt][rg]);
          }
        }
      }
    }
  }
}

extern "C" void kernel_launch(void* const* d_in, const int* in_sizes, int n_in,
                              void* d_out, int out_size, void* d_ws,
                              size_t ws_size, hipStream_t stream) {
  const float* x = (const float*)d_in[0];      // [8192, 1024] f32
  const float* rw = (const float*)d_in[1];     // [8, 1024] f32
  const float* fcw = (const float*)d_in[2];    // [8, 2048, 1024] f32
  const float* pjw = (const float*)d_in[3];    // [8, 1024, 2048] f32
  float* out = (float*)d_out;                  // [8192,1024] ++ [8192,8] f32
  float* rw_out = out + (size_t)NTOK * NC;

  // Workspace layout:
  // cnt 256B | tok 128KB | wslot 128KB | epair 32KB | wpair 64KB |
  // xb 16.78MB | fcwb 33.55MB | pjwb 33.55MB | hidden (mch ladder)
  char* ws = (char*)d_ws;
  int* cnt = (int*)ws;                              // 256 B
  int* tok = (int*)(ws + 256);                      // 128 KB
  float* wslot = (float*)(ws + 256 + 131072);       // 128 KB
  int* epair = (int*)(ws + 262400);                 // 32 KB
  float* wpair = (float*)(ws + 262400 + 32768);     // 64 KB
  bf16* xb = (bf16*)(ws + 360704);                  // 16.78 MB
  bf16* fcwb = (bf16*)(ws + 360704 + 16777216);     // 33.55 MB
  bf16* pjwb = (bf16*)(ws + 360704 + 16777216 + 33554432);
  const size_t fixed = 360704 + 16777216 + 2 * 33554432;  // 84.25 MB
  bf16* hidden = (bf16*)(ws + fixed);               // NE * mch * NH bf16
  (void)in_sizes; (void)n_in; (void)out_size;

  int mch = 256;
  for (int cand = CAP; cand >= 256; cand >>= 1) {
    const size_t need = fixed + (size_t)NE * cand * NH * 2;
    if (need <= ws_size) { mch = cand; break; }
  }

  zero_out_kernel<<<NTOK * NC / 1024, 256, 0, stream>>>(out);
  cvt_kernel<<<NE * NH * NC / 2048, 256, 0, stream>>>(fcw, fcwb);
  cvt_kernel<<<NE * NC * NH / 2048, 256, 0, stream>>>(pjw, pjwb);
  router_kernel<<<NTOK / 4, 256, 0, stream>>>(x, rw, rw_out, epair, wpair, xb);
  build_kernel<<<NE, 256, 0, stream>>>(epair, wpair, cnt, tok, wslot);

  for (int c = 0; c < CAP / mch; ++c) {
    // fc: N=H=2048, K=C=1024, gather bf16 x, relu^2 -> hidden chunk
    gemm_moe<true><<<NE * (NH / 256) * (mch / 256), 512, 0, stream>>>(
        xb, hidden, fcwb, hidden, out, cnt, tok, wslot, c * mch, mch);
    // proj: N=C=1024, K=H=2048, combine w*val into out via f32 atomics
    gemm_moe<false><<<NE * (NC / 256) * (mch / 256), 512, 0, stream>>>(
        xb, hidden, pjwb, hidden, out, cnt, tok, wslot, c * mch, mch);
  }
}

// Round 6
// 467.253 us; speedup vs baseline: 1.0612x; 1.0612x over previous
//
#include <hip/hip_runtime.h>
#include <hip/hip_bf16.h>
#include <stdint.h>

// Problem constants: B=4, T=2048, C=1024, E=8, H=2048, K=2
#define NB 4
#define NTT 2048
#define NC 1024
#define NE 8
#define NH 2048
#define NKK 2
#define NTOK (NB * NTT)            // 8192
#define CAP (2 * NTOK * NKK / NE)  // 4096

typedef __hip_bfloat16 bf16;
typedef __attribute__((ext_vector_type(8))) short short8;
typedef __attribute__((ext_vector_type(4))) short short4v;
typedef __attribute__((ext_vector_type(4))) float floatx4;
typedef __attribute__((ext_vector_type(2))) float floatx2;

typedef const __attribute__((address_space(1))) void* gas_ptr;
typedef __attribute__((address_space(3))) void* las_ptr;

static __device__ __forceinline__ void async_copy16(const void* g, void* l) {
  // 16B/lane; LDS dest = wave-uniform base + lane*16 (m97/m104 semantics).
  __builtin_amdgcn_global_load_lds((gas_ptr)g, (las_ptr)l, 16, 0, 0);
}

static __device__ __forceinline__ unsigned short f2b(float f) {
  bf16 h = __float2bfloat16(f);
  unsigned short u;
  __builtin_memcpy(&u, &h, 2);
  return u;
}
static __device__ __forceinline__ int iclamp(int v, int lo, int hi) {
  return v < lo ? lo : (v > hi ? hi : v);
}

__global__ __launch_bounds__(256) void zero_out_kernel(float* __restrict__ out) {
  const size_t i = ((size_t)blockIdx.x * 256 + threadIdx.x) * 4;
  floatx4 z = {0.f, 0.f, 0.f, 0.f};
  *reinterpret_cast<floatx4*>(out + i) = z;
}

// f32 -> bf16 (RNE), 8 elements/thread, TWO tensors in one dispatch
// (fcw then pjw; saves a launch gap). Each half is 8192 blocks.
__global__ __launch_bounds__(256) void cvt2_kernel(
    const float* __restrict__ src0, bf16* __restrict__ dst0,
    const float* __restrict__ src1, bf16* __restrict__ dst1, int halfBlocks) {
  const int b = blockIdx.x;
  const float* src = (b < halfBlocks) ? src0 : src1;
  bf16* dst = (b < halfBlocks) ? dst0 : dst1;
  const int lb = (b < halfBlocks) ? b : b - halfBlocks;
  const size_t i = ((size_t)lb * 256 + threadIdx.x) * 8;
  const floatx4 a = *reinterpret_cast<const floatx4*>(src + i);
  const floatx4 c = *reinterpret_cast<const floatx4*>(src + i + 4);
  short8 r;
  r[0] = (short)f2b(a[0]); r[1] = (short)f2b(a[1]);
  r[2] = (short)f2b(a[2]); r[3] = (short)f2b(a[3]);
  r[4] = (short)f2b(c[0]); r[5] = (short)f2b(c[1]);
  r[6] = (short)f2b(c[2]); r[7] = (short)f2b(c[3]);
  *reinterpret_cast<short8*>(dst + i) = r;
}

// Router v3 (atomic-free; round-2 fix for the 196-us cnt[] cacheline chain).
// Writes packed top-2 (epair) + normalized weights (wpair); slot assignment
// moved to build_kernel (scan). Emits x_bf16 (free: x is read anyway).
__global__ __launch_bounds__(256) void router_kernel(
    const float* __restrict__ x, const float* __restrict__ rw,
    float* __restrict__ rw_out, int* __restrict__ epair,
    float* __restrict__ wpair, bf16* __restrict__ xb) {
  __shared__ float rws[NE * NC];  // 32 KB
  const int tid = threadIdx.x;
  {
    const floatx4* rw4 = reinterpret_cast<const floatx4*>(rw);
    floatx4* rwl4 = reinterpret_cast<floatx4*>(rws);
#pragma unroll
    for (int i = 0; i < 8; ++i) rwl4[i * 256 + tid] = rw4[i * 256 + tid];
  }
  __syncthreads();

  const int wave = tid >> 6;
  const int lane = tid & 63;
  const int t = blockIdx.x * 4 + wave;
  const floatx4* xr4 = reinterpret_cast<const floatx4*>(x + (size_t)t * NC);
  const floatx4* rwl4 = reinterpret_cast<const floatx4*>(rws);
  bf16* xbr = xb + (size_t)t * NC;

  floatx4 xv[4];
#pragma unroll
  for (int i = 0; i < 4; ++i) xv[i] = xr4[i * 64 + lane];

#pragma unroll
  for (int i = 0; i < 4; ++i) {
    const int idx = i * 64 + lane;
    short4v o;
    o[0] = (short)f2b(xv[i][0]); o[1] = (short)f2b(xv[i][1]);
    o[2] = (short)f2b(xv[i][2]); o[3] = (short)f2b(xv[i][3]);
    *reinterpret_cast<short4v*>(xbr + idx * 4) = o;
  }

  float acc[NE];
#pragma unroll
  for (int e = 0; e < NE; ++e) acc[e] = 0.f;
#pragma unroll
  for (int i = 0; i < 4; ++i) {
    const int idx = i * 64 + lane;
#pragma unroll
    for (int e = 0; e < NE; ++e) {
      const floatx4 wv = rwl4[e * 256 + idx];
      acc[e] = fmaf(xv[i][0], wv[0], acc[e]);
      acc[e] = fmaf(xv[i][1], wv[1], acc[e]);
      acc[e] = fmaf(xv[i][2], wv[2], acc[e]);
      acc[e] = fmaf(xv[i][3], wv[3], acc[e]);
    }
  }
#pragma unroll
  for (int e = 0; e < NE; ++e) {
#pragma unroll
    for (int off = 32; off; off >>= 1) acc[e] += __shfl_xor(acc[e], off, 64);
  }

  float m = acc[0];
#pragma unroll
  for (int e = 1; e < NE; ++e) m = fmaxf(m, acc[e]);
  float p[NE];
  float s = 0.f;
#pragma unroll
  for (int e = 0; e < NE; ++e) {
    p[e] = __expf(acc[e] - m);
    s += p[e];
  }
  const float inv = 1.f / s;
#pragma unroll
  for (int e = 0; e < NE; ++e) p[e] *= inv;

  if (lane < NE) rw_out[(size_t)t * NE + lane] = p[lane];

  if (lane == 0) {
    int i0 = 0;
    float v0 = p[0];
    int i1 = -1;
    float v1 = -1.f;
#pragma unroll
    for (int e = 1; e < NE; ++e) {
      if (p[e] > v0) {
        v1 = v0; i1 = i0;
        v0 = p[e]; i0 = e;
      } else if (p[e] > v1) {
        v1 = p[e]; i1 = e;
      }
    }
    i0 = iclamp(i0, 0, NE - 1);
    i1 = iclamp(i1, 0, NE - 1);
    const float denom = v0 + v1 + 1e-10f;
    epair[t] = i0 | (i1 << 16);
    floatx2 wv;
    wv[0] = v0 / denom;
    wv[1] = v1 / denom;
    *reinterpret_cast<floatx2*>(wpair + 2 * t) = wv;
  }
}

// One block per expert; contiguous 32-token chunks per thread; block scan ->
// slot bases. Slot order = flat-index order = reference stable argsort,
// including capacity-overflow drop order. Zero global atomics.
__global__ __launch_bounds__(256) void build_kernel(
    const int* __restrict__ epair, const float* __restrict__ wpair,
    int* __restrict__ cnt, int* __restrict__ tok, float* __restrict__ wslot) {
  const int e = blockIdx.x;
  const int tid = threadIdx.x;
  const int lane = tid & 63;
  const int wave = tid >> 6;
  constexpr int TPT = NTOK / 256;  // 32 tokens per thread
  const int t0 = tid * TPT;

  int pe[TPT];
#pragma unroll
  for (int i = 0; i < TPT; i += 4) {
    const int4 v = *reinterpret_cast<const int4*>(epair + t0 + i);
    pe[i] = v.x; pe[i + 1] = v.y; pe[i + 2] = v.z; pe[i + 3] = v.w;
  }
  int c = 0;
#pragma unroll
  for (int i = 0; i < TPT; ++i)
    c += (((pe[i] & 0xffff) == e) ? 1 : 0) + (((pe[i] >> 16) == e) ? 1 : 0);

  int incl = c;
#pragma unroll
  for (int off = 1; off < 64; off <<= 1) {
    const int up = __shfl_up(incl, off, 64);
    if (lane >= off) incl += up;
  }
  __shared__ int wsum[4];
  if (lane == 63) wsum[wave] = incl;
  __syncthreads();
  int base = incl - c;
#pragma unroll
  for (int w = 0; w < 4; ++w)
    if (w < wave) base += wsum[w];
  if (tid == 255) cnt[e] = base + c;  // total (may exceed CAP; gemm clamps)

#pragma unroll
  for (int i = 0; i < TPT; ++i) {
    const int t = t0 + i;
    if ((pe[i] & 0xffff) == e) {
      if (base < CAP) {
        tok[e * CAP + base] = t;
        wslot[e * CAP + base] = wpair[2 * t];
      }
      ++base;
    }
    if ((pe[i] >> 16) == e) {
      if (base < CAP) {
        tok[e * CAP + base] = t;
        wslot[e * CAP + base] = wpair[2 * t + 1];
      }
      ++base;
    }
  }
}

// Grouped GEMM v4 (round-6): REVERT to the proven round-3 structure
// (128x128 tile, BK=64, 4 waves, single-buffer m97 staging, 162 us/disp,
// best measured) -- round-4/5's 256-sq schedule ports both landed at
// MfmaUtil ~15.7% (m232 "8-phase-shaped but not functioning"). One change
// grafted on: FLAT grid with e = bid & 7 -> all blocks of one expert land
// on one XCD (round-5 PROVED this cuts FETCH 3x). At 128-sq the gather
// panel (4 MB) + weight panel (4 MB) become XCD-L2-resident, converting
// ~900-cyc HBM-latency staging misses into ~200-cyc L2 hits, which the
// ~5-blocks/CU occupancy CAN convert into time (unlike 1-block/CU 256-sq).
// FC=1: A = x_bf16 gathered via tok, relu^2 -> hidden chunk (bf16).
// FC=0: A = hidden chunk, epilogue f32 atomicAdd of w*val into out.
template <bool FC>
__global__ __launch_bounds__(256) void gemm_moe(
    const bf16* __restrict__ Axb, const bf16* __restrict__ Ah,
    const bf16* __restrict__ Bw, bf16* __restrict__ Oh,
    float* __restrict__ Oo, const int* __restrict__ cnt,
    const int* __restrict__ tok, const float* __restrict__ wslot,
    int rowOffset, int mch) {
  constexpr int Kd = FC ? NC : NH;
  constexpr int Nd = FC ? NH : NC;
  constexpr int NXB = Nd / 128;  // col blocks: 16 (fc) / 8 (proj)

  const int bid = blockIdx.x;
  const int e = bid & 7;  // expert -> XCD co-residency (bid%8 == XCD id)
  const int rest = bid >> 3;
  const int xb_ = rest % NXB;
  const int yb_ = rest / NXB;

  const int Me = iclamp(cnt[e], 0, CAP);
  const int rowBase = rowOffset + yb_ * 128;  // expert-local row
  if (rowBase >= Me) return;
  const int colBase = xb_ * 128;

  const bf16* __restrict__ Be = Bw + (size_t)e * Nd * Kd;
  const bf16* __restrict__ Ahc = Ah + (size_t)e * mch * NH;

  __shared__ bf16 As[128 * 64];
  __shared__ bf16 Bs[128 * 64];

  const int tid = threadIdx.x;
  const int lane = tid & 63;
  const int wid = tid >> 6;
  const int wm = wid & 1;
  const int wn = wid >> 1;
  const int ml = lane & 15;
  const int quad = lane >> 4;

  // Staging: slot sidx holds (row r = sidx>>3, phys chunk pc = sidx&7);
  // data placed there is logical chunk lc = pc ^ (r&7).
  const bf16* ga[4];
  const bf16* gb[4];
  bf16* la[4];
  bf16* lb[4];
#pragma unroll
  for (int it = 0; it < 4; ++it) {
    const int sidx = it * 256 + tid;
    const int r = sidx >> 3;
    const int pc = sidx & 7;
    const int lc = pc ^ (r & 7);
    if (FC) {
      const int grow = rowBase + r;
      const int tk = (grow < Me) ? tok[e * CAP + grow] : 0;
      const int arow = iclamp(tk, 0, NTOK - 1);  // global token row in x_bf16
      ga[it] = Axb + (size_t)arow * NC + lc * 8;
    } else {
      int grow = rowBase + r;
      if (grow > Me - 1) grow = Me - 1;  // stay inside this expert's rows
      const int arow = iclamp(grow - rowOffset, 0, mch - 1);  // chunk-local
      ga[it] = Ahc + (size_t)arow * NH + lc * 8;
    }
    gb[it] = Be + (size_t)(colBase + r) * Kd + lc * 8;
    la[it] = As + sidx * 8;
    lb[it] = Bs + sidx * 8;
  }

  floatx4 acc[4][4];
#pragma unroll
  for (int mt = 0; mt < 4; ++mt)
#pragma unroll
    for (int nt = 0; nt < 4; ++nt) acc[mt][nt] = floatx4{0.f, 0.f, 0.f, 0.f};

  // Fragment LDS element offsets (per lane): row = ..+ml, chunk q = kk*4+quad
  int aoff[4][2], boff[4][2];
#pragma unroll
  for (int t4 = 0; t4 < 4; ++t4)
#pragma unroll
    for (int kk = 0; kk < 2; ++kk) {
      const int ra = wm * 64 + t4 * 16 + ml;
      const int rb = wn * 64 + t4 * 16 + ml;
      const int q = kk * 4 + quad;
      aoff[t4][kk] = (ra * 8 + (q ^ (ra & 7))) * 8;
      boff[t4][kk] = (rb * 8 + (q ^ (rb & 7))) * 8;
    }

  // Prologue: stage tile k0=0
#pragma unroll
  for (int it = 0; it < 4; ++it) async_copy16(ga[it], la[it]);
#pragma unroll
  for (int it = 0; it < 4; ++it) async_copy16(gb[it], lb[it]);

  const int nkb = Kd >> 6;
  for (int kb = 0; kb < nkb; ++kb) {
    __syncthreads();  // drains vmcnt -> LDS tile ready
    short8 af[4][2], bff[4][2];
#pragma unroll
    for (int mt = 0; mt < 4; ++mt)
#pragma unroll
      for (int kk = 0; kk < 2; ++kk)
        af[mt][kk] = *reinterpret_cast<const short8*>(&As[aoff[mt][kk]]);
#pragma unroll
    for (int nt = 0; nt < 4; ++nt)
#pragma unroll
      for (int kk = 0; kk < 2; ++kk)
        bff[nt][kk] = *reinterpret_cast<const short8*>(&Bs[boff[nt][kk]]);
#pragma unroll
    for (int kk = 0; kk < 2; ++kk)
#pragma unroll
      for (int mt = 0; mt < 4; ++mt)
#pragma unroll
        for (int nt = 0; nt < 4; ++nt)
          acc[mt][nt] = __builtin_amdgcn_mfma_f32_16x16x32_bf16(
              af[mt][kk], bff[nt][kk], acc[mt][nt], 0, 0, 0);
    __syncthreads();  // all ds_reads done before restage
    if (kb + 1 < nkb) {
      const int k0 = (kb + 1) << 6;
#pragma unroll
      for (int it = 0; it < 4; ++it) async_copy16(ga[it] + k0, la[it]);
#pragma unroll
      for (int it = 0; it < 4; ++it) async_copy16(gb[it] + k0, lb[it]);
    }
  }

  // Epilogue: C/D layout col=lane&15, row=quad*4+reg (m89/m91 verified).
  if (FC) {
    bf16* __restrict__ O = Oh + (size_t)e * mch * NH;
    const int rlBase = rowBase - rowOffset;  // chunk-local
#pragma unroll
    for (int mt = 0; mt < 4; ++mt) {
      const int rl = wm * 64 + mt * 16 + quad * 4;
#pragma unroll
      for (int nt = 0; nt < 4; ++nt) {
        const int cc = colBase + wn * 64 + nt * 16 + ml;
        const floatx4 v = acc[mt][nt];
#pragma unroll
        for (int rg = 0; rg < 4; ++rg) {
          if (rowBase + rl + rg < Me) {
            float f = fmaxf(v[rg], 0.f);
            f = f * f;  // relu^2
            O[(size_t)(rlBase + rl + rg) * NH + cc] = __float2bfloat16(f);
          }
        }
      }
    }
  } else {
#pragma unroll
    for (int mt = 0; mt < 4; ++mt) {
      const int rl = wm * 64 + mt * 16 + quad * 4;
#pragma unroll
      for (int rg = 0; rg < 4; ++rg) {
        const int re = rowBase + rl + rg;  // expert-local row
        if (re < Me) {
          const int t = iclamp(tok[e * CAP + re], 0, NTOK - 1);
          const float w = wslot[e * CAP + re];
#pragma unroll
          for (int nt = 0; nt < 4; ++nt) {
            const int cc = colBase + wn * 64 + nt * 16 + ml;
            atomicAdd(Oo + (size_t)t * NC + cc, w * acc[mt][nt][rg]);
          }
        }
      }
    }
  }
}

extern "C" void kernel_launch(void* const* d_in, const int* in_sizes, int n_in,
                              void* d_out, int out_size, void* d_ws,
                              size_t ws_size, hipStream_t stream) {
  const float* x = (const float*)d_in[0];      // [8192, 1024] f32
  const float* rw = (const float*)d_in[1];     // [8, 1024] f32
  const float* fcw = (const float*)d_in[2];    // [8, 2048, 1024] f32
  const float* pjw = (const float*)d_in[3];    // [8, 1024, 2048] f32
  float* out = (float*)d_out;                  // [8192,1024] ++ [8192,8] f32
  float* rw_out = out + (size_t)NTOK * NC;

  // Workspace layout:
  // cnt 256B | tok 128KB | wslot 128KB | epair 32KB | wpair 64KB |
  // xb 16.78MB | fcwb 33.55MB | pjwb 33.55MB | hidden (mch ladder)
  char* ws = (char*)d_ws;
  int* cnt = (int*)ws;                              // 256 B
  int* tok = (int*)(ws + 256);                      // 128 KB
  float* wslot = (float*)(ws + 256 + 131072);       // 128 KB
  int* epair = (int*)(ws + 262400);                 // 32 KB
  float* wpair = (float*)(ws + 262400 + 32768);     // 64 KB
  bf16* xb = (bf16*)(ws + 360704);                  // 16.78 MB
  bf16* fcwb = (bf16*)(ws + 360704 + 16777216);     // 33.55 MB
  bf16* pjwb = (bf16*)(ws + 360704 + 16777216 + 33554432);
  const size_t fixed = 360704 + 16777216 + 2 * 33554432;  // 84.25 MB
  bf16* hidden = (bf16*)(ws + fixed);               // NE * mch * NH bf16
  (void)in_sizes; (void)n_in; (void)out_size;

  int mch = 128;
  for (int cand = CAP; cand >= 128; cand >>= 1) {
    const size_t need = fixed + (size_t)NE * cand * NH * 2;
    if (need <= ws_size) { mch = cand; break; }
  }

  zero_out_kernel<<<NTOK * NC / 1024, 256, 0, stream>>>(out);
  cvt2_kernel<<<2 * (NE * NH * NC / 2048), 256, 0, stream>>>(
      fcw, fcwb, pjw, pjwb, NE * NH * NC / 2048);
  router_kernel<<<NTOK / 4, 256, 0, stream>>>(x, rw, rw_out, epair, wpair, xb);
  build_kernel<<<NE, 256, 0, stream>>>(epair, wpair, cnt, tok, wslot);

  for (int c = 0; c < CAP / mch; ++c) {
    // fc: N=H=2048, K=C=1024, gather bf16 x, relu^2 -> hidden chunk
    gemm_moe<true><<<NE * (NH / 128) * (mch / 128), 256, 0, stream>>>(
        xb, hidden, fcwb, hidden, out, cnt, tok, wslot, c * mch, mch);
    // proj: N=C=1024, K=H=2048, combine w*val into out via f32 atomics
    gemm_moe<false><<<NE * (NC / 128) * (mch / 128), 256, 0, stream>>>(
        xb, hidden, pjwb, hidden, out, cnt, tok, wslot, c * mch, mch);
  }
}